// Round 16
// baseline (4870.224 us; speedup 1.0000x reference)
//
#include <hip/hip_runtime.h>
#include <stdint.h>

// ---------------------------------------------------------------------------
// AWD-LSTM eval forward.  T=256, B=256, H=1024, FEAT=319 (=300+7+12), C=13.
// Layer1's recurrent carry is ignored by the reference -> only layer0 is
// sequential; layer1+decoder are parallel over rows.
// Round 16: occupancy ladder final rung -- 32 waves/CU via K-split.
// Ladder: 1 blk/CU=18.7us, 2=17.4, 4 (16 waves/CU)=12.3 us/step.  Tile area
// fixes frag count (16 waves/CU at 1 frag/wave), so double waves via K-split:
// same 32Mx32N tile + grid 1024 (traffic unchanged), 512-thread blocks =
// 8 waves: wave (kc,q) = quadrant q over K-half kc (21 iters).  4 staging
// roles/half x 1 gload/iter (balanced), vmcnt(2) ring, 1 barrier/iter.
// Partial accs summed via LDS epi (unioned onto stage bufs; 32 KB/block ->
// 4 blocks/CU = 2048 thr = CU max).  launch_bounds(512,8) caps VGPR<=64.
// l1gemm/decode/prep = R15 verbatim.
// GEMMs: bf16 MFMA 16x16x32, f32 accum; weights gate-interleaved
// (col 4j+p = gate p of unit j) so the LSTM cell fuses into the epilogue.
// ---------------------------------------------------------------------------

typedef __attribute__((ext_vector_type(8))) short bf16x8;
typedef __attribute__((ext_vector_type(4))) float f32x4;

#define SLOT 262144ull  // 256*1024 elements per (B,H) slab

__device__ __forceinline__ uint16_t f2bf(float f) {
  uint32_t u = __float_as_uint(f);
  u += 0x7fffu + ((u >> 16) & 1u);
  return (uint16_t)(u >> 16);
}
__device__ __forceinline__ float bf2f(uint16_t h) {
  return __uint_as_float(((uint32_t)h) << 16);
}
__device__ __forceinline__ float sigmoidf_(float x) {
  return __builtin_amdgcn_rcpf(1.0f + __expf(-x));
}
__device__ __forceinline__ float tanhf_(float x) {
  return 1.0f - 2.0f * __builtin_amdgcn_rcpf(__expf(2.0f * x) + 1.0f);
}
__device__ __forceinline__ void gload_lds16(const void* g, void* l) {
  __builtin_amdgcn_global_load_lds(
      (const __attribute__((address_space(1))) void*)g,
      (__attribute__((address_space(3))) void*)l, 16, 0, 0);
}
// LDS tile: row-major [rows][32 k] bf16; four 16B chunks of each row stored
// permuted: chunk_pos = chunk ^ ((row>>1)&3)  -> ~2-way banks
__device__ __forceinline__ bf16x8 lds_frag(const uint16_t* base, int row, int kc) {
  const uint16_t* p = base + row * 32 + ((kc ^ ((row >> 1) & 3)) << 3);
  return *(const bf16x8*)p;
}
__device__ __forceinline__ f32x4 mfma16(bf16x8 a, bf16x8 b, f32x4 c) {
  return __builtin_amdgcn_mfma_f32_16x16x32_bf16(a, b, c, 0, 0, 0);
}

// ---------------- weight prep ----------------
__global__ __launch_bounds__(256) void k_prep_w0(
    const float* __restrict__ wi0, const float* __restrict__ bi0,
    const float* __restrict__ wh0, const float* __restrict__ bh0,
    uint16_t* __restrict__ W0c, float* __restrict__ b0) {
  int r = blockIdx.x;            // interleaved output row: unit j, gate p
  int p = r & 3, j = r >> 2;
  int src = p * 1024 + j;
  const float* wi = wi0 + (size_t)src * 319;
  const float* wh = wh0 + (size_t)src * 1024;
  uint16_t* dst = W0c + (size_t)r * 1344;
  for (int k = threadIdx.x; k < 1344; k += 256) {
    float v;
    if (k < 319) v = wi[k];
    else if (k == 319) v = 0.0f;
    else v = wh[k - 320];
    dst[k] = f2bf(v);
  }
  if (threadIdx.x == 0) b0[r] = bi0[src] + bh0[src];
}

__global__ __launch_bounds__(256) void k_prep_w1(
    const float* __restrict__ wi1, const float* __restrict__ bi1,
    const float* __restrict__ wh1, const float* __restrict__ bh1,
    uint16_t* __restrict__ W1c, float* __restrict__ b1) {
  int r = blockIdx.x;
  int p = r & 3, j = r >> 2;
  int src = p * 1024 + j;
  const float* wi = wi1 + (size_t)src * 1024;
  const float* wh = wh1 + (size_t)src * 1024;
  uint16_t* dst = W1c + (size_t)r * 2048;
  for (int k = threadIdx.x; k < 2048; k += 256) {
    float v = (k < 1024) ? wi[k] : wh[k - 1024];
    dst[k] = f2bf(v);
  }
  if (threadIdx.x == 0) b1[r] = bi1[src] + bh1[src];
}

__global__ __launch_bounds__(256) void k_init(
    const float* __restrict__ h_init, const float* __restrict__ c_init,
    uint16_t* __restrict__ h_slot, float* __restrict__ c_state) {
  int i = blockIdx.x * 256 + threadIdx.x;  // 262144 = 256*1024
  h_slot[i] = f2bf(h_init[i]);             // layer0 slice of h_init
  c_state[i] = c_init[i];
}

// ---------------- embedding + concat -> x_bf ----------------
__global__ __launch_bounds__(256) void k_embed(
    const int* __restrict__ tokens, const float* __restrict__ casing,
    const float* __restrict__ pos, const float* __restrict__ emb,
    uint16_t* __restrict__ x_bf) {
  int row = blockIdx.x * 4 + (threadIdx.x >> 6);  // (t*256+b)
  int l = threadIdx.x & 63;
  int tok = tokens[row];
  const float* er = emb + (size_t)tok * 300;
  uint16_t* xr = x_bf + (size_t)row * 320;
#pragma unroll
  for (int c0 = 0; c0 < 320; c0 += 64) {
    int c = c0 + l;
    float v;
    if (c < 300) v = er[c];
    else if (c < 307) v = casing[(size_t)row * 7 + (c - 300)];
    else if (c < 319) v = pos[(size_t)row * 12 + (c - 307)];
    else v = 0.0f;
    xr[c] = f2bf(v);
  }
}

// ---------------- layer0 sequential step ----------------
// GEMM [256 x 1344] @ [4096 x 1344]^T, tile 32M x 32N, grid 1024, 512-thread
// blocks = 8 waves (4 blocks/CU = 32 waves/CU).  Wave (kc = w>>2, q = w&3):
// computes quadrant q (16x16) over K-half kc (21 of 42 K-tiles).  Staging
// role = q: 0/1 -> A 16-row halves, 2/3 -> B 16-col halves (1 gload/iter
// each).  4-buffer ring per half, vmcnt(2/1/0), one barrier/iter.  Partial
// accs summed via epi LDS (unioned onto stage bufs).  1 cell/thread (kc=0).
// XCD-chunked swizzle: XCD k owns col-tiles [16k,16k+16) (1.4 MB W, L2-res).
__global__ __launch_bounds__(512, 8) void k_step(
    const uint16_t* __restrict__ x_t, const uint16_t* __restrict__ W0c,
    const float* __restrict__ b0, const uint16_t* __restrict__ h_in,
    uint16_t* __restrict__ h_out, uint16_t* __restrict__ c0_out,
    float* __restrict__ c_state) {
  __shared__ __align__(16) char smem[32768];  // 2 halves x (A 8K + B 8K)
  int tid = threadIdx.x;
  int w = tid >> 6, l = tid & 63;
  int kc = w >> 2, q = w & 3;   // K-half, quadrant (=staging role)
  int wr = q >> 1, wc = q & 1;
  int lid = (blockIdx.x & 7) * 128 + (blockIdx.x >> 3);  // bijective 1024=8*128
  int Mb = (lid & 7) * 32;      // batch tile (32 rows)
  int Nb = (lid >> 3) * 32;     // output-col tile (32 interleaved cols)
  f32x4 acc = {};

  int sc = (l & 3) ^ ((l >> 3) & 3);  // global chunk for this lane's LDS slot
  const uint16_t* xrow =
      x_t + (size_t)(Mb + (q & 1) * 16 + (l >> 2)) * 320 + sc * 8;
  const uint16_t* hrow =
      h_in + (size_t)(Mb + (q & 1) * 16 + (l >> 2)) * 1024 + sc * 8;
  const uint16_t* wrow =
      W0c + (size_t)(Nb + (q & 1) * 16 + (l >> 2)) * 1344 + sc * 8;
  char* halfbase = smem + kc * 16384;

  auto stage = [&](int i) {  // i = half-local iter; global K-tile kc*21+i
    int buf = i & 3;
    int kt = kc * 21 + i;
    int kg = kt * 32;
    if (q < 2) {
      const uint16_t* sA = (kt < 10) ? (xrow + kg) : (hrow + (kg - 320));
      gload_lds16(sA, halfbase + buf * 2048 + q * 1024);
    } else {
      gload_lds16(wrow + kg, halfbase + 8192 + buf * 2048 + (q - 2) * 1024);
    }
  };

  stage(0);
  stage(1);
  stage(2);
  for (int i = 0; i < 21; ++i) {
    __builtin_amdgcn_sched_barrier(0);
    if (i < 19) asm volatile("s_waitcnt vmcnt(2)" ::: "memory");
    else if (i == 19) asm volatile("s_waitcnt vmcnt(1)" ::: "memory");
    else asm volatile("s_waitcnt vmcnt(0)" ::: "memory");
    __builtin_amdgcn_s_barrier();
    __builtin_amdgcn_sched_barrier(0);
    if (i < 18) stage(i + 3);
    const uint16_t* Ab = (const uint16_t*)(halfbase + (i & 3) * 2048);
    const uint16_t* Bb = (const uint16_t*)(halfbase + 8192 + (i & 3) * 2048);
    bf16x8 a0 = lds_frag(Ab, wr * 16 + (l & 15), l >> 4);
    bf16x8 q0 = lds_frag(Bb, wc * 16 + (l & 15), l >> 4);
    acc = mfma16(a0, q0, acc);
  }

  __syncthreads();  // all K-loop LDS reads done -> reuse smem as epi
  float* epif = (float*)smem;  // [q][kc][16][20] f32 = 10240 B
#pragma unroll
  for (int r = 0; r < 4; ++r)
    epif[((q * 2 + kc) * 16 + (l >> 4) * 4 + r) * 20 + (l & 15)] = acc[r];
  __syncthreads();  // cross-wave epi visibility

  if (kc == 0) {    // 256 threads: 1 LSTM cell each (32 rows x 8 units)
    int rr = l >> 2, j = l & 3;
    int jbase = (Nb + wc * 16) >> 2;
    f32x4 q0 = *(const f32x4*)&epif[((q * 2 + 0) * 16 + rr) * 20 + j * 4];
    f32x4 q1 = *(const f32x4*)&epif[((q * 2 + 1) * 16 + rr) * 20 + j * 4];
    f32x4 bv = *(const f32x4*)&b0[(jbase + j) * 4];
    float vi = sigmoidf_(q0[0] + q1[0] + bv[0]);
    float vf = sigmoidf_(q0[1] + q1[1] + bv[1]);
    float vo = sigmoidf_(q0[2] + q1[2] + bv[2]);
    float vg = tanhf_(q0[3] + q1[3] + bv[3]);
    int bg = Mb + wr * 16 + rr;
    int jg = jbase + j;
    size_t sidx = (size_t)bg * 1024 + jg;
    float cold = c_state[sidx];
    float cn = vf * cold + vi * vg;
    float hh = vo * tanhf_(cn);
    c_state[sidx] = cn;
    c0_out[sidx] = f2bf(cn);
    h_out[sidx] = f2bf(hh);
  }
}

// ---------------- layer1 GEMM over one chunk (R15 verbatim) ----------------
// rows = CH*256; A row (t,b) = [h0(t,b) | h0(t,255-b)]  (slot tl of h0buf).
// tile 128x128, 4 waves (2x2) x (4x4 frags), fused cell epilogue.
// 1-D grid 64*CH, XCD-chunked swizzle; 3-buffer vmcnt(4) ring; LDS 48 KB
// (epilogue unioned) -> 3 blocks/CU.
__global__ __launch_bounds__(256, 3) void k_l1gemm(
    const uint16_t* __restrict__ h0buf, const uint16_t* __restrict__ W1c,
    const float* __restrict__ b1, const uint16_t* __restrict__ c0buf,
    uint16_t* __restrict__ h1buf) {
  __shared__ __align__(16) char smem[49152];  // 3 x (As 8192 + Bs 8192)
  float* epif = (float*)smem;                 // [4][16][68] f32 = 17408 B
  int tid = threadIdx.x;
  int w = tid >> 6, l = tid & 63;
  int wr = w >> 1, wc = w & 1;
  uint32_t G = gridDim.x;          // 64*CH (divisible by 8)
  uint32_t cpx = G >> 3;
  uint32_t lid = (blockIdx.x & 7) * cpx + (blockIdx.x >> 3);  // bijective
  uint32_t yyTot = G >> 5;         // 2*CH row-tiles per N-panel
  uint32_t nb = lid / yyTot;       // N-panel 0..31
  uint32_t yy = lid - nb * yyTot;  // row tile 0..2CH-1
  int Nb = (int)nb * 128;
  int tl = (int)(yy >> 1);
  int bbase = (int)(yy & 1) * 128;
  const uint16_t* hrow = h0buf + (size_t)tl * SLOT;
  const uint16_t* c0s = c0buf + (size_t)tl * SLOT;
  uint16_t* h1s = h1buf + (size_t)tl * SLOT;
  f32x4 acc[4][4] = {};

  int sc = (l & 3) ^ ((l >> 3) & 3);
  int srow0 = (w * 2 + 0) * 16 + (l >> 2);
  int srow1 = (w * 2 + 1) * 16 + (l >> 2);
  const uint16_t* hA0n = hrow + (size_t)(bbase + srow0) * 1024;
  const uint16_t* hA0f = hrow + (size_t)(255 - (bbase + srow0)) * 1024;
  const uint16_t* hA1n = hrow + (size_t)(bbase + srow1) * 1024;
  const uint16_t* hA1f = hrow + (size_t)(255 - (bbase + srow1)) * 1024;
  const uint16_t* wB0 = W1c + (size_t)(Nb + srow0) * 2048;
  const uint16_t* wB1 = W1c + (size_t)(Nb + srow1) * 2048;

  auto stage = [&](int kt, int buf) {
    int kg = kt * 32 + sc * 8;
    const uint16_t* sA0 = (kg < 1024) ? (hA0n + kg) : (hA0f + (kg - 1024));
    const uint16_t* sA1 = (kg < 1024) ? (hA1n + kg) : (hA1f + (kg - 1024));
    char* base = smem + buf * 16384;
    gload_lds16(sA0, base + (w * 2 + 0) * 1024);
    gload_lds16(sA1, base + (w * 2 + 1) * 1024);
    gload_lds16(wB0 + kg, base + 8192 + (w * 2 + 0) * 1024);
    gload_lds16(wB1 + kg, base + 8192 + (w * 2 + 1) * 1024);
  };

  stage(0, 0);
  stage(1, 1);
  for (int kt = 0; kt < 64; ++kt) {
    __builtin_amdgcn_sched_barrier(0);
    if (kt < 63) asm volatile("s_waitcnt vmcnt(4)" ::: "memory");
    else asm volatile("s_waitcnt vmcnt(0)" ::: "memory");
    __builtin_amdgcn_s_barrier();
    __builtin_amdgcn_sched_barrier(0);
    if (kt < 62) stage(kt + 2, (kt + 2) % 3);
    const uint16_t* As = (const uint16_t*)(smem + (kt % 3) * 16384);
    const uint16_t* Bs = As + 4096;
    bf16x8 a[4], q[4];
#pragma unroll
    for (int m = 0; m < 4; ++m) a[m] = lds_frag(As, wr * 64 + m * 16 + (l & 15), l >> 4);
#pragma unroll
    for (int n = 0; n < 4; ++n) q[n] = lds_frag(Bs, wc * 64 + n * 16 + (l & 15), l >> 4);
#pragma unroll
    for (int m = 0; m < 4; ++m)
#pragma unroll
      for (int n = 0; n < 4; ++n) acc[m][n] = mfma16(a[m], q[n], acc[m][n]);
  }
  __syncthreads();  // all reads of smem tiles done -> safe to reuse as epi

  int jbase = (Nb + wc * 64) >> 2;
#pragma unroll
  for (int m = 0; m < 4; ++m) {
#pragma unroll
    for (int n = 0; n < 4; ++n)
#pragma unroll
      for (int r = 0; r < 4; ++r)
        epif[((size_t)w * 16 + (l >> 4) * 4 + r) * 68 + n * 16 + (l & 15)] =
            acc[m][n][r];
    asm volatile("s_waitcnt lgkmcnt(0)" ::: "memory");
#pragma unroll
    for (int it = 0; it < 4; ++it) {
      int pp = it * 64 + l;
      int rr = pp >> 4, j = pp & 15;
      f32x4 q = *(const f32x4*)&epif[((size_t)w * 16 + rr) * 68 + j * 4];
      f32x4 bv = *(const f32x4*)&b1[(size_t)(jbase + j) * 4];
      float vi = sigmoidf_(q[0] + bv[0]);
      float vf = sigmoidf_(q[1] + bv[1]);
      float vo = sigmoidf_(q[2] + bv[2]);
      float vg = tanhf_(q[3] + bv[3]);
      int rowl = wr * 64 + m * 16 + rr;
      int b = bbase + rowl;
      int jg = jbase + j;
      float c0v = bf2f(c0s[(size_t)(255 - b) * 1024 + jg]);
      float cn = vf * c0v + vi * vg;
      float hh = vo * tanhf_(cn);
      h1s[(size_t)b * 1024 + jg] = f2bf(hh);
    }
    asm volatile("s_waitcnt lgkmcnt(0)" ::: "memory");
  }
}

// ---------------- decoder over one chunk ----------------
__global__ __launch_bounds__(256) void k_decode(
    const uint16_t* __restrict__ h0buf, const uint16_t* __restrict__ h1buf,
    const float* __restrict__ dec_w, const float* __restrict__ dec_b,
    float* __restrict__ out, int t0) {
  int rowl = blockIdx.x * 4 + (threadIdx.x >> 6);  // chunk-local row
  int l = threadIdx.x & 63;
  int tl = rowl >> 8, b = rowl & 255;
  const uint16_t* h0 = h0buf + (size_t)tl * SLOT + (size_t)b * 1024;
  const uint16_t* h1 = h1buf + (size_t)tl * SLOT + (size_t)b * 1024;
  float acc[13];
#pragma unroll
  for (int c = 0; c < 13; ++c) acc[c] = 0.0f;
#pragma unroll
  for (int part = 0; part < 2; ++part) {
    const uint16_t* h = part ? h1 : h0;
    const float* wb = dec_w + part * 1024 + (size_t)l * 16;
    float hv[16];
    const bf16x8* hp = (const bf16x8*)(h + l * 16);
    bf16x8 v0 = hp[0];
    bf16x8 v1 = hp[1];
#pragma unroll
    for (int jj = 0; jj < 8; ++jj) {
      hv[jj] = bf2f((uint16_t)v0[jj]);
      hv[8 + jj] = bf2f((uint16_t)v1[jj]);
    }
#pragma unroll
    for (int c = 0; c < 13; ++c) {
      const float* wc = wb + (size_t)c * 2048;
      float s = 0.0f;
#pragma unroll
      for (int jj = 0; jj < 16; ++jj) s += hv[jj] * wc[jj];
      acc[c] += s;
    }
  }
#pragma unroll
  for (int c = 0; c < 13; ++c) {
    float v = acc[c];
#pragma unroll
    for (int off = 32; off > 0; off >>= 1) v += __shfl_xor(v, off, 64);
    acc[c] = v;
  }
  if (l == 0) {
    int t = t0 + tl;
    float* orow = out + ((size_t)t * 256 + b) * 13;
#pragma unroll
    for (int c = 0; c < 13; ++c) orow[c] = acc[c] + dec_b[c];
  }
}

// ---------------- host ----------------
extern "C" void kernel_launch(void* const* d_in, const int* in_sizes, int n_in,
                              void* d_out, int out_size, void* d_ws, size_t ws_size,
                              hipStream_t stream) {
  const int* tokens = (const int*)d_in[0];
  const float* casing = (const float*)d_in[1];
  const float* pos = (const float*)d_in[2];
  const float* emb = (const float*)d_in[3];
  const float* wi0 = (const float*)d_in[4];
  const float* bi0 = (const float*)d_in[5];
  const float* wh0 = (const float*)d_in[6];
  const float* bh0 = (const float*)d_in[7];
  const float* wi1 = (const float*)d_in[8];
  const float* bi1 = (const float*)d_in[9];
  const float* wh1 = (const float*)d_in[10];
  const float* bh1 = (const float*)d_in[11];
  const float* dec_w = (const float*)d_in[12];
  const float* dec_b = (const float*)d_in[13];
  const float* h_init = (const float*)d_in[14];
  const float* c_init = (const float*)d_in[15];
  float* out = (float*)d_out;
  (void)in_sizes; (void)n_in; (void)out_size;

  char* ws = (char*)d_ws;
  size_t off = 0;
  auto alloc = [&](size_t bytes) {
    char* p = ws + off;
    off += (bytes + 255) & ~(size_t)255;
    return p;
  };
  // fixed buffers (~69 MB)
  uint16_t* W0c = (uint16_t*)alloc(4096ull * 1344 * 2);
  float* b0 = (float*)alloc(4096 * 4);
  uint16_t* W1c = (uint16_t*)alloc(4096ull * 2048 * 2);
  float* b1 = (float*)alloc(4096 * 4);
  uint16_t* x_bf = (uint16_t*)alloc(65536ull * 320 * 2);
  float* c_st = (float*)alloc(SLOT * 4);

  // chunk size: (CH+1) + CH + CH slots of SLOT*2 bytes
  const size_t SB = SLOT * 2;  // 524288, 256-aligned
  int CH = 0;
  for (int c = 64; c >= 2; c >>= 1) {
    if (off + (size_t)(3 * c + 1) * SB + 4096 <= ws_size) { CH = c; break; }
  }
  if (CH == 0) return;  // ws too small (diagnostic: poisoned output)
  uint16_t* h0buf = (uint16_t*)alloc((size_t)(CH + 1) * SB);  // slot CH = h_init
  uint16_t* c0buf = (uint16_t*)alloc((size_t)CH * SB);
  uint16_t* h1buf = (uint16_t*)alloc((size_t)CH * SB);

  k_prep_w0<<<4096, 256, 0, stream>>>(wi0, bi0, wh0, bh0, W0c, b0);
  k_prep_w1<<<4096, 256, 0, stream>>>(wi1, bi1, wh1, bh1, W1c, b1);
  k_embed<<<16384, 256, 0, stream>>>(tokens, casing, pos, emb, x_bf);
  k_init<<<1024, 256, 0, stream>>>(h_init, c_init, h0buf + (size_t)CH * SLOT,
                                   c_st);

  for (int t0 = 0; t0 < 256; t0 += CH) {
    for (int tl = 0; tl < CH; ++tl) {
      int t = t0 + tl;
      // input slot: tl-1; first step reads prev chunk's last slot (CH-1),
      // intact until its tl==CH-1 rewrite -- or h_init slot CH at t=0.
      int in_s = (tl > 0) ? (tl - 1) : ((t0 == 0) ? CH : CH - 1);
      k_step<<<1024, 512, 0, stream>>>(
          x_bf + (size_t)t * 81920, W0c, b0,
          h0buf + (size_t)in_s * SLOT,
          h0buf + (size_t)tl * SLOT,
          c0buf + (size_t)tl * SLOT, c_st);
    }
    k_l1gemm<<<64 * CH, 256, 0, stream>>>(h0buf, W1c, b1, c0buf, h1buf);
    k_decode<<<CH * 64, 256, 0, stream>>>(h0buf, h1buf, dec_w, dec_b, out, t0);
  }
}

// Round 17
// 4701.913 us; speedup vs baseline: 1.0358x; 1.0358x over previous
//
#include <hip/hip_runtime.h>
#include <stdint.h>

// ---------------------------------------------------------------------------
// AWD-LSTM eval forward.  T=256, B=256, H=1024, FEAT=319 (=300+7+12), C=13.
// Layer1's recurrent carry is ignored by the reference -> only layer0 is
// sequential; layer1+decoder are parallel over rows.
// Round 17 = Round 15 verbatim (best: 4691 us).  R16's 32-waves/CU K-split
// regressed (13.0 vs 12.3 us/step: double barrier convoy + epi reduction ate
// the occupancy gain) -> occupancy ladder saturated at 4 blocks/CU x 256 thr.
// Structure floor: layer0 = 256 dependent dispatches x ~12.3 us (launch-
// serialized recurrence; 6 in-kernel barrier designs all >= launch path),
// l1gemm ~930 TF (2-barrier structure ceiling), decode/prep ~0.35 ms.
// GEMMs: bf16 MFMA 16x16x32, f32 accum; weights gate-interleaved
// (col 4j+p = gate p of unit j) so the LSTM cell fuses into the epilogue.
// ---------------------------------------------------------------------------

typedef __attribute__((ext_vector_type(8))) short bf16x8;
typedef __attribute__((ext_vector_type(4))) float f32x4;

#define SLOT 262144ull  // 256*1024 elements per (B,H) slab

__device__ __forceinline__ uint16_t f2bf(float f) {
  uint32_t u = __float_as_uint(f);
  u += 0x7fffu + ((u >> 16) & 1u);
  return (uint16_t)(u >> 16);
}
__device__ __forceinline__ float bf2f(uint16_t h) {
  return __uint_as_float(((uint32_t)h) << 16);
}
__device__ __forceinline__ float sigmoidf_(float x) {
  return __builtin_amdgcn_rcpf(1.0f + __expf(-x));
}
__device__ __forceinline__ float tanhf_(float x) {
  return 1.0f - 2.0f * __builtin_amdgcn_rcpf(__expf(2.0f * x) + 1.0f);
}
__device__ __forceinline__ void gload_lds16(const void* g, void* l) {
  __builtin_amdgcn_global_load_lds(
      (const __attribute__((address_space(1))) void*)g,
      (__attribute__((address_space(3))) void*)l, 16, 0, 0);
}
// LDS tile: row-major [rows][32 k] bf16; four 16B chunks of each row stored
// permuted: chunk_pos = chunk ^ ((row>>1)&3)  -> ~2-way banks
__device__ __forceinline__ bf16x8 lds_frag(const uint16_t* base, int row, int kc) {
  const uint16_t* p = base + row * 32 + ((kc ^ ((row >> 1) & 3)) << 3);
  return *(const bf16x8*)p;
}
__device__ __forceinline__ f32x4 mfma16(bf16x8 a, bf16x8 b, f32x4 c) {
  return __builtin_amdgcn_mfma_f32_16x16x32_bf16(a, b, c, 0, 0, 0);
}

// ---------------- weight prep ----------------
__global__ __launch_bounds__(256) void k_prep_w0(
    const float* __restrict__ wi0, const float* __restrict__ bi0,
    const float* __restrict__ wh0, const float* __restrict__ bh0,
    uint16_t* __restrict__ W0c, float* __restrict__ b0) {
  int r = blockIdx.x;            // interleaved output row: unit j, gate p
  int p = r & 3, j = r >> 2;
  int src = p * 1024 + j;
  const float* wi = wi0 + (size_t)src * 319;
  const float* wh = wh0 + (size_t)src * 1024;
  uint16_t* dst = W0c + (size_t)r * 1344;
  for (int k = threadIdx.x; k < 1344; k += 256) {
    float v;
    if (k < 319) v = wi[k];
    else if (k == 319) v = 0.0f;
    else v = wh[k - 320];
    dst[k] = f2bf(v);
  }
  if (threadIdx.x == 0) b0[r] = bi0[src] + bh0[src];
}

__global__ __launch_bounds__(256) void k_prep_w1(
    const float* __restrict__ wi1, const float* __restrict__ bi1,
    const float* __restrict__ wh1, const float* __restrict__ bh1,
    uint16_t* __restrict__ W1c, float* __restrict__ b1) {
  int r = blockIdx.x;
  int p = r & 3, j = r >> 2;
  int src = p * 1024 + j;
  const float* wi = wi1 + (size_t)src * 1024;
  const float* wh = wh1 + (size_t)src * 1024;
  uint16_t* dst = W1c + (size_t)r * 2048;
  for (int k = threadIdx.x; k < 2048; k += 256) {
    float v = (k < 1024) ? wi[k] : wh[k - 1024];
    dst[k] = f2bf(v);
  }
  if (threadIdx.x == 0) b1[r] = bi1[src] + bh1[src];
}

__global__ __launch_bounds__(256) void k_init(
    const float* __restrict__ h_init, const float* __restrict__ c_init,
    uint16_t* __restrict__ h_slot, float* __restrict__ c_state) {
  int i = blockIdx.x * 256 + threadIdx.x;  // 262144 = 256*1024
  h_slot[i] = f2bf(h_init[i]);             // layer0 slice of h_init
  c_state[i] = c_init[i];
}

// ---------------- embedding + concat -> x_bf ----------------
__global__ __launch_bounds__(256) void k_embed(
    const int* __restrict__ tokens, const float* __restrict__ casing,
    const float* __restrict__ pos, const float* __restrict__ emb,
    uint16_t* __restrict__ x_bf) {
  int row = blockIdx.x * 4 + (threadIdx.x >> 6);  // (t*256+b)
  int l = threadIdx.x & 63;
  int tok = tokens[row];
  const float* er = emb + (size_t)tok * 300;
  uint16_t* xr = x_bf + (size_t)row * 320;
#pragma unroll
  for (int c0 = 0; c0 < 320; c0 += 64) {
    int c = c0 + l;
    float v;
    if (c < 300) v = er[c];
    else if (c < 307) v = casing[(size_t)row * 7 + (c - 300)];
    else if (c < 319) v = pos[(size_t)row * 12 + (c - 307)];
    else v = 0.0f;
    xr[c] = f2bf(v);
  }
}

// ---------------- layer0 sequential step ----------------
// GEMM [256 x 1344] @ [4096 x 1344]^T, tile 32M x 32N, grid 1024
// (4 blocks/CU), 4 waves 2x2 over (16M,16N).  Waves 0/1 stage A halves,
// waves 2/3 stage B halves (1 KB each/iter).  4-buffer ring, vmcnt(2/1/0),
// one barrier/iter.  Fused LSTM cell: 1 cell/thread.
// XCD-chunked swizzle: XCD k owns col-tiles [16k,16k+16) (1.4 MB W, L2-res).
__global__ __launch_bounds__(256, 4) void k_step(
    const uint16_t* __restrict__ x_t, const uint16_t* __restrict__ W0c,
    const float* __restrict__ b0, const uint16_t* __restrict__ h_in,
    uint16_t* __restrict__ h_out, uint16_t* __restrict__ c0_out,
    float* __restrict__ c_state) {
  __shared__ __align__(16) uint16_t As[4][1024];  // 32 rows x 32 k
  __shared__ __align__(16) uint16_t Bs[4][1024];  // 32 rows x 32 k
  __shared__ __align__(16) float epi[4][16][20];
  int tid = threadIdx.x;
  int w = tid >> 6, l = tid & 63;
  int wr = w >> 1, wc = w & 1;
  int lid = (blockIdx.x & 7) * 128 + (blockIdx.x >> 3);  // bijective 1024=8*128
  int Mb = (lid & 7) * 32;    // batch tile (32 rows)
  int Nb = (lid >> 3) * 32;   // output-col tile (32 interleaved cols)
  f32x4 acc = {};

  // staging roles: w=0/1 -> A half w (16 rows); w=2/3 -> B half w&1.
  // lane -> row l>>2 within half, LDS chunk slot l&3, global chunk sc.
  int sc = (l & 3) ^ ((l >> 3) & 3);
  const uint16_t* xrow =
      x_t + (size_t)(Mb + (w & 1) * 16 + (l >> 2)) * 320 + sc * 8;
  const uint16_t* hrow =
      h_in + (size_t)(Mb + (w & 1) * 16 + (l >> 2)) * 1024 + sc * 8;
  const uint16_t* wrow =
      W0c + (size_t)(Nb + (w & 1) * 16 + (l >> 2)) * 1344 + sc * 8;

  auto stage = [&](int kt, int buf) {
    int kg = kt * 32;
    if (w < 2) {
      const uint16_t* sA = (kt < 10) ? (xrow + kg) : (hrow + (kg - 320));
      gload_lds16(sA, &As[buf][w * 512]);
    } else {
      gload_lds16(wrow + kg, &Bs[buf][(w & 1) * 512]);
    }
  };

  stage(0, 0);
  stage(1, 1);
  stage(2, 2);
  for (int kt = 0; kt < 42; ++kt) {
    __builtin_amdgcn_sched_barrier(0);
    if (kt < 40) asm volatile("s_waitcnt vmcnt(2)" ::: "memory");
    else if (kt == 40) asm volatile("s_waitcnt vmcnt(1)" ::: "memory");
    else asm volatile("s_waitcnt vmcnt(0)" ::: "memory");
    __builtin_amdgcn_s_barrier();
    __builtin_amdgcn_sched_barrier(0);
    if (kt < 39) stage(kt + 3, (kt + 3) & 3);
    const uint16_t* Ab = As[kt & 3];
    const uint16_t* Bb = Bs[kt & 3];
    bf16x8 a0 = lds_frag(Ab, wr * 16 + (l & 15), l >> 4);
    bf16x8 q0 = lds_frag(Bb, wc * 16 + (l & 15), l >> 4);
    acc = mfma16(a0, q0, acc);
  }

  // fused LSTM cell epilogue: wave covers 16 rows x 16 cols; after the epi
  // redistribution each lane owns ONE cell (row rr, unit jbase+j: 4 gates
  // are 4 consecutive interleaved cols).
  int jbase = (Nb + wc * 16) >> 2;
#pragma unroll
  for (int r = 0; r < 4; ++r)
    epi[w][(l >> 4) * 4 + r][l & 15] = acc[r];
  asm volatile("s_waitcnt lgkmcnt(0)" ::: "memory");
  {
    int rr = l >> 2, j = l & 3;
    f32x4 q = *(const f32x4*)&epi[w][rr][j * 4];
    f32x4 bv = *(const f32x4*)&b0[(jbase + j) * 4];
    float vi = sigmoidf_(q[0] + bv[0]);
    float vf = sigmoidf_(q[1] + bv[1]);
    float vo = sigmoidf_(q[2] + bv[2]);
    float vg = tanhf_(q[3] + bv[3]);
    int bg = Mb + wr * 16 + rr;
    int jg = jbase + j;
    size_t sidx = (size_t)bg * 1024 + jg;
    float cold = c_state[sidx];
    float cn = vf * cold + vi * vg;
    float hh = vo * tanhf_(cn);
    c_state[sidx] = cn;
    c0_out[sidx] = f2bf(cn);
    h_out[sidx] = f2bf(hh);
  }
}

// ---------------- layer1 GEMM over one chunk ----------------
// rows = CH*256; A row (t,b) = [h0(t,b) | h0(t,255-b)]  (slot tl of h0buf).
// tile 128x128, 4 waves (2x2) x (4x4 frags), fused cell epilogue.
// 1-D grid 64*CH, XCD-chunked swizzle; 3-buffer vmcnt(4) ring; LDS 48 KB
// (epilogue unioned) -> 3 blocks/CU.
__global__ __launch_bounds__(256, 3) void k_l1gemm(
    const uint16_t* __restrict__ h0buf, const uint16_t* __restrict__ W1c,
    const float* __restrict__ b1, const uint16_t* __restrict__ c0buf,
    uint16_t* __restrict__ h1buf) {
  __shared__ __align__(16) char smem[49152];  // 3 x (As 8192 + Bs 8192)
  float* epif = (float*)smem;                 // [4][16][68] f32 = 17408 B
  int tid = threadIdx.x;
  int w = tid >> 6, l = tid & 63;
  int wr = w >> 1, wc = w & 1;
  uint32_t G = gridDim.x;          // 64*CH (divisible by 8)
  uint32_t cpx = G >> 3;
  uint32_t lid = (blockIdx.x & 7) * cpx + (blockIdx.x >> 3);  // bijective
  uint32_t yyTot = G >> 5;         // 2*CH row-tiles per N-panel
  uint32_t nb = lid / yyTot;       // N-panel 0..31
  uint32_t yy = lid - nb * yyTot;  // row tile 0..2CH-1
  int Nb = (int)nb * 128;
  int tl = (int)(yy >> 1);
  int bbase = (int)(yy & 1) * 128;
  const uint16_t* hrow = h0buf + (size_t)tl * SLOT;
  const uint16_t* c0s = c0buf + (size_t)tl * SLOT;
  uint16_t* h1s = h1buf + (size_t)tl * SLOT;
  f32x4 acc[4][4] = {};

  int sc = (l & 3) ^ ((l >> 3) & 3);
  int srow0 = (w * 2 + 0) * 16 + (l >> 2);
  int srow1 = (w * 2 + 1) * 16 + (l >> 2);
  const uint16_t* hA0n = hrow + (size_t)(bbase + srow0) * 1024;
  const uint16_t* hA0f = hrow + (size_t)(255 - (bbase + srow0)) * 1024;
  const uint16_t* hA1n = hrow + (size_t)(bbase + srow1) * 1024;
  const uint16_t* hA1f = hrow + (size_t)(255 - (bbase + srow1)) * 1024;
  const uint16_t* wB0 = W1c + (size_t)(Nb + srow0) * 2048;
  const uint16_t* wB1 = W1c + (size_t)(Nb + srow1) * 2048;

  auto stage = [&](int kt, int buf) {
    int kg = kt * 32 + sc * 8;
    const uint16_t* sA0 = (kg < 1024) ? (hA0n + kg) : (hA0f + (kg - 1024));
    const uint16_t* sA1 = (kg < 1024) ? (hA1n + kg) : (hA1f + (kg - 1024));
    char* base = smem + buf * 16384;
    gload_lds16(sA0, base + (w * 2 + 0) * 1024);
    gload_lds16(sA1, base + (w * 2 + 1) * 1024);
    gload_lds16(wB0 + kg, base + 8192 + (w * 2 + 0) * 1024);
    gload_lds16(wB1 + kg, base + 8192 + (w * 2 + 1) * 1024);
  };

  stage(0, 0);
  stage(1, 1);
  for (int kt = 0; kt < 64; ++kt) {
    __builtin_amdgcn_sched_barrier(0);
    if (kt < 63) asm volatile("s_waitcnt vmcnt(4)" ::: "memory");
    else asm volatile("s_waitcnt vmcnt(0)" ::: "memory");
    __builtin_amdgcn_s_barrier();
    __builtin_amdgcn_sched_barrier(0);
    if (kt < 62) stage(kt + 2, (kt + 2) % 3);
    const uint16_t* As = (const uint16_t*)(smem + (kt % 3) * 16384);
    const uint16_t* Bs = As + 4096;
    bf16x8 a[4], q[4];
#pragma unroll
    for (int m = 0; m < 4; ++m) a[m] = lds_frag(As, wr * 64 + m * 16 + (l & 15), l >> 4);
#pragma unroll
    for (int n = 0; n < 4; ++n) q[n] = lds_frag(Bs, wc * 64 + n * 16 + (l & 15), l >> 4);
#pragma unroll
    for (int m = 0; m < 4; ++m)
#pragma unroll
      for (int n = 0; n < 4; ++n) acc[m][n] = mfma16(a[m], q[n], acc[m][n]);
  }
  __syncthreads();  // all reads of smem tiles done -> safe to reuse as epi

  int jbase = (Nb + wc * 64) >> 2;
#pragma unroll
  for (int m = 0; m < 4; ++m) {
#pragma unroll
    for (int n = 0; n < 4; ++n)
#pragma unroll
      for (int r = 0; r < 4; ++r)
        epif[((size_t)w * 16 + (l >> 4) * 4 + r) * 68 + n * 16 + (l & 15)] =
            acc[m][n][r];
    asm volatile("s_waitcnt lgkmcnt(0)" ::: "memory");
#pragma unroll
    for (int it = 0; it < 4; ++it) {
      int pp = it * 64 + l;
      int rr = pp >> 4, j = pp & 15;
      f32x4 q = *(const f32x4*)&epif[((size_t)w * 16 + rr) * 68 + j * 4];
      f32x4 bv = *(const f32x4*)&b1[(size_t)(jbase + j) * 4];
      float vi = sigmoidf_(q[0] + bv[0]);
      float vf = sigmoidf_(q[1] + bv[1]);
      float vo = sigmoidf_(q[2] + bv[2]);
      float vg = tanhf_(q[3] + bv[3]);
      int rowl = wr * 64 + m * 16 + rr;
      int b = bbase + rowl;
      int jg = jbase + j;
      float c0v = bf2f(c0s[(size_t)(255 - b) * 1024 + jg]);
      float cn = vf * c0v + vi * vg;
      float hh = vo * tanhf_(cn);
      h1s[(size_t)b * 1024 + jg] = f2bf(hh);
    }
    asm volatile("s_waitcnt lgkmcnt(0)" ::: "memory");
  }
}

// ---------------- decoder over one chunk ----------------
__global__ __launch_bounds__(256) void k_decode(
    const uint16_t* __restrict__ h0buf, const uint16_t* __restrict__ h1buf,
    const float* __restrict__ dec_w, const float* __restrict__ dec_b,
    float* __restrict__ out, int t0) {
  int rowl = blockIdx.x * 4 + (threadIdx.x >> 6);  // chunk-local row
  int l = threadIdx.x & 63;
  int tl = rowl >> 8, b = rowl & 255;
  const uint16_t* h0 = h0buf + (size_t)tl * SLOT + (size_t)b * 1024;
  const uint16_t* h1 = h1buf + (size_t)tl * SLOT + (size_t)b * 1024;
  float acc[13];
#pragma unroll
  for (int c = 0; c < 13; ++c) acc[c] = 0.0f;
#pragma unroll
  for (int part = 0; part < 2; ++part) {
    const uint16_t* h = part ? h1 : h0;
    const float* wb = dec_w + part * 1024 + (size_t)l * 16;
    float hv[16];
    const bf16x8* hp = (const bf16x8*)(h + l * 16);
    bf16x8 v0 = hp[0];
    bf16x8 v1 = hp[1];
#pragma unroll
    for (int jj = 0; jj < 8; ++jj) {
      hv[jj] = bf2f((uint16_t)v0[jj]);
      hv[8 + jj] = bf2f((uint16_t)v1[jj]);
    }
#pragma unroll
    for (int c = 0; c < 13; ++c) {
      const float* wc = wb + (size_t)c * 2048;
      float s = 0.0f;
#pragma unroll
      for (int jj = 0; jj < 16; ++jj) s += hv[jj] * wc[jj];
      acc[c] += s;
    }
  }
#pragma unroll
  for (int c = 0; c < 13; ++c) {
    float v = acc[c];
#pragma unroll
    for (int off = 32; off > 0; off >>= 1) v += __shfl_xor(v, off, 64);
    acc[c] = v;
  }
  if (l == 0) {
    int t = t0 + tl;
    float* orow = out + ((size_t)t * 256 + b) * 13;
#pragma unroll
    for (int c = 0; c < 13; ++c) orow[c] = acc[c] + dec_b[c];
  }
}

// ---------------- host ----------------
extern "C" void kernel_launch(void* const* d_in, const int* in_sizes, int n_in,
                              void* d_out, int out_size, void* d_ws, size_t ws_size,
                              hipStream_t stream) {
  const int* tokens = (const int*)d_in[0];
  const float* casing = (const float*)d_in[1];
  const float* pos = (const float*)d_in[2];
  const float* emb = (const float*)d_in[3];
  const float* wi0 = (const float*)d_in[4];
  const float* bi0 = (const float*)d_in[5];
  const float* wh0 = (const float*)d_in[6];
  const float* bh0 = (const float*)d_in[7];
  const float* wi1 = (const float*)d_in[8];
  const float* bi1 = (const float*)d_in[9];
  const float* wh1 = (const float*)d_in[10];
  const float* bh1 = (const float*)d_in[11];
  const float* dec_w = (const float*)d_in[12];
  const float* dec_b = (const float*)d_in[13];
  const float* h_init = (const float*)d_in[14];
  const float* c_init = (const float*)d_in[15];
  float* out = (float*)d_out;
  (void)in_sizes; (void)n_in; (void)out_size;

  char* ws = (char*)d_ws;
  size_t off = 0;
  auto alloc = [&](size_t bytes) {
    char* p = ws + off;
    off += (bytes + 255) & ~(size_t)255;
    return p;
  };
  // fixed buffers (~69 MB)
  uint16_t* W0c = (uint16_t*)alloc(4096ull * 1344 * 2);
  float* b0 = (float*)alloc(4096 * 4);
  uint16_t* W1c = (uint16_t*)alloc(4096ull * 2048 * 2);
  float* b1 = (float*)alloc(4096 * 4);
  uint16_t* x_bf = (uint16_t*)alloc(65536ull * 320 * 2);
  float* c_st = (float*)alloc(SLOT * 4);

  // chunk size: (CH+1) + CH + CH slots of SLOT*2 bytes
  const size_t SB = SLOT * 2;  // 524288, 256-aligned
  int CH = 0;
  for (int c = 64; c >= 2; c >>= 1) {
    if (off + (size_t)(3 * c + 1) * SB + 4096 <= ws_size) { CH = c; break; }
  }
  if (CH == 0) return;  // ws too small (diagnostic: poisoned output)
  uint16_t* h0buf = (uint16_t*)alloc((size_t)(CH + 1) * SB);  // slot CH = h_init
  uint16_t* c0buf = (uint16_t*)alloc((size_t)CH * SB);
  uint16_t* h1buf = (uint16_t*)alloc((size_t)CH * SB);

  k_prep_w0<<<4096, 256, 0, stream>>>(wi0, bi0, wh0, bh0, W0c, b0);
  k_prep_w1<<<4096, 256, 0, stream>>>(wi1, bi1, wh1, bh1, W1c, b1);
  k_embed<<<16384, 256, 0, stream>>>(tokens, casing, pos, emb, x_bf);
  k_init<<<1024, 256, 0, stream>>>(h_init, c_init, h0buf + (size_t)CH * SLOT,
                                   c_st);

  for (int t0 = 0; t0 < 256; t0 += CH) {
    for (int tl = 0; tl < CH; ++tl) {
      int t = t0 + tl;
      // input slot: tl-1; first step reads prev chunk's last slot (CH-1),
      // intact until its tl==CH-1 rewrite -- or h_init slot CH at t=0.
      int in_s = (tl > 0) ? (tl - 1) : ((t0 == 0) ? CH : CH - 1);
      k_step<<<1024, 256, 0, stream>>>(
          x_bf + (size_t)t * 81920, W0c, b0,
          h0buf + (size_t)in_s * SLOT,
          h0buf + (size_t)tl * SLOT,
          c0buf + (size_t)tl * SLOT, c_st);
    }
    k_l1gemm<<<64 * CH, 256, 0, stream>>>(h0buf, W1c, b1, c0buf, h1buf);
    k_decode<<<CH * 64, 256, 0, stream>>>(h0buf, h1buf, dec_w, dec_b, out, t0);
  }
}